// Round 1
// baseline (76.623 us; speedup 1.0000x reference)
//
#include <hip/hip_runtime.h>

// DirectVolumeStratifiedFrontToBackRenderer — MI355X
// Ray-march 256x256 rays x 320 samples through a 256^3 f32 volume.
// alpha is constant 0.1 inside the [-1,1]^3 local cube (density volume is
// constant, and in f32 (1-0.1f+1e-10)==0.9f, (1+1e-10)==1.0f), so outside
// samples are exact no-ops. Output = per-image standardize + minmax, at
// out[w*256+h].

#define SEGS 4
#define PPT 80   // 320 / SEGS

__global__ __launch_bounds__(256) void render_kernel(
    const float* __restrict__ vol,
    const float* __restrict__ camR,
    const float* __restrict__ camT,
    float* __restrict__ gray)
{
    const int lane = threadIdx.x & 63;
    const int seg  = threadIdx.x >> 6;
    const int pix  = blockIdx.x * 64 + lane;
    const int w = pix & 255;
    const int h = pix >> 8;

    // camera (B=1). Rt = R^T; origin = -Rt*T; dir = Rt*dir_cam.
    const float R00=camR[0],R01=camR[1],R02=camR[2];
    const float R10=camR[3],R11=camR[4],R12=camR[5];
    const float R20=camR[6],R21=camR[7],R22=camR[8];
    const float T0=camT[0],T1=camT[1],T2=camT[2];

    const float ox = -(R00*T0 + R10*T1 + R20*T2);
    const float oy = -(R01*T0 + R11*T1 + R21*T2);
    const float oz = -(R02*T0 + R12*T1 + R22*T2);

    const float FOVT = 0.57735026918962576f;   // tan(30 deg)
    const float gx = -1.0f + w * (2.0f/255.0f);
    const float gy = -1.0f + h * (2.0f/255.0f);
    const float dcx = gx*FOVT, dcy = gy*FOVT;  // dcz = 1

    const float dx = R00*dcx + R10*dcy + R20;
    const float dy = R01*dcx + R11*dcy + R21;
    const float dz = R02*dcx + R12*dcy + R22;

    // half = 255 * (3/256) * 0.5 = 1.494140625 (exact in f32)
    const float inv_half = (float)(1.0 / 1.494140625);
    const float DSTEP = 4.0f / 319.0f;

    float T = 1.0f;
    float rgb = 0.0f;
    const int p0 = seg * PPT;

    #pragma unroll 4
    for (int i = 0; i < PPT; ++i) {
        const float d = 2.0f + (float)(p0 + i) * DSTEP;
        const float px = fmaf(dx, d, ox) * inv_half;
        const float py = fmaf(dy, d, oy) * inv_half;
        const float pz = fmaf(dz, d, oz) * inv_half;
        if (fabsf(px) <= 1.0f && fabsf(py) <= 1.0f && fabsf(pz) <= 1.0f) {
            const float fx = (px + 1.0f) * 127.5f;
            const float fy = (py + 1.0f) * 127.5f;
            const float fz = (pz + 1.0f) * 127.5f;
            const float x0f = floorf(fx), y0f = floorf(fy), z0f = floorf(fz);
            const float wx = fx - x0f, wy = fy - y0f, wz = fz - z0f;
            int x0 = (int)x0f, y0 = (int)y0f, z0 = (int)z0f;
            x0 = max(0, min(x0, 255));
            y0 = max(0, min(y0, 255));
            z0 = max(0, min(z0, 255));
            const int x1 = min(x0 + 1, 255);
            const int y1 = min(y0 + 1, 255);
            const int z1 = min(z0 + 1, 255);
            const int zy00 = (z0*256 + y0) << 8;
            const int zy01 = (z0*256 + y1) << 8;
            const int zy10 = (z1*256 + y0) << 8;
            const int zy11 = (z1*256 + y1) << 8;
            const float v000 = vol[zy00+x0], v001 = vol[zy00+x1];
            const float v010 = vol[zy01+x0], v011 = vol[zy01+x1];
            const float v100 = vol[zy10+x0], v101 = vol[zy10+x1];
            const float v110 = vol[zy11+x0], v111 = vol[zy11+x1];
            const float c00 = fmaf(wx, v001 - v000, v000);
            const float c01 = fmaf(wx, v011 - v010, v010);
            const float c10 = fmaf(wx, v101 - v100, v100);
            const float c11 = fmaf(wx, v111 - v110, v110);
            const float c0 = fmaf(wy, c01 - c00, c00);
            const float c1 = fmaf(wy, c11 - c10, c10);
            const float v  = fmaf(wz, c1 - c0, c0);
            rgb = fmaf(0.1f * T, v, rgb);
            T *= 0.9f;
        }
        // outside: trans multiplier is (1 + 1e-10) == 1.0f in f32 -> no-op
    }

    __shared__ float s_rgb[SEGS][64];
    __shared__ float s_T[SEGS][64];
    s_rgb[seg][lane] = rgb;
    s_T[seg][lane]   = T;
    __syncthreads();

    if (threadIdx.x < 64) {
        const int l = threadIdx.x;
        float total = s_rgb[0][l];
        float Ta    = s_T[0][l];
        total = fmaf(Ta, s_rgb[1][l], total); Ta *= s_T[1][l];
        total = fmaf(Ta, s_rgb[2][l], total); Ta *= s_T[2][l];
        total = fmaf(Ta, s_rgb[3][l], total);
        const int pp = blockIdx.x * 64 + l;
        const int ww = pp & 255, hh = pp >> 8;
        // screen = transpose(rgba,(0,3,2,1)) -> out[w*256 + h]
        gray[ww * 256 + hh] = total;
    }
}

__global__ __launch_bounds__(1024) void reduce_kernel(
    const float* __restrict__ g, float* __restrict__ params)
{
    __shared__ double s_sum[1024];
    __shared__ double s_sq[1024];
    __shared__ float  s_mn[1024];
    __shared__ float  s_mx[1024];

    const int tid = threadIdx.x;
    double sum = 0.0, sq = 0.0;
    float mn = 3.4e38f, mx = -3.4e38f;
    for (int i = tid; i < 65536; i += 1024) {
        const float v = g[i];
        sum += (double)v;
        sq  += (double)v * (double)v;
        mn = fminf(mn, v);
        mx = fmaxf(mx, v);
    }
    s_sum[tid] = sum; s_sq[tid] = sq; s_mn[tid] = mn; s_mx[tid] = mx;
    __syncthreads();
    for (int s = 512; s > 0; s >>= 1) {
        if (tid < s) {
            s_sum[tid] += s_sum[tid + s];
            s_sq[tid]  += s_sq[tid + s];
            s_mn[tid]   = fminf(s_mn[tid], s_mn[tid + s]);
            s_mx[tid]   = fmaxf(s_mx[tid], s_mx[tid + s]);
        }
        __syncthreads();
    }
    if (tid == 0) {
        const double N = 65536.0;
        const double mean = s_sum[0] / N;
        double var = (s_sq[0] - s_sum[0] * s_sum[0] / N) / (N - 1.0);
        if (var < 0.0) var = 0.0;
        params[0] = (float)mean;
        params[1] = (float)sqrt(var) + 1e-8f;   // std(ddof=1) + EPS
        params[2] = s_mn[0];
        params[3] = s_mx[0];
    }
}

__global__ __launch_bounds__(256) void finalize_kernel(
    float* __restrict__ g, const float* __restrict__ params)
{
    const int i = blockIdx.x * 256 + threadIdx.x;
    const float mean = params[0], sd = params[1];
    const float mn = params[2],  mx = params[3];
    const float z    = (g[i] - mean) / sd;
    const float zmin = (mn   - mean) / sd;
    const float zmax = (mx   - mean) / sd;
    g[i] = (z - zmin + 1e-8f) / (zmax - zmin + 1e-8f);
}

extern "C" void kernel_launch(void* const* d_in, const int* in_sizes, int n_in,
                              void* d_out, int out_size, void* d_ws, size_t ws_size,
                              hipStream_t stream)
{
    const float* vol  = (const float*)d_in[0];   // (1,1,256,256,256) f32
    const float* camR = (const float*)d_in[1];   // (1,3,3)
    const float* camT = (const float*)d_in[2];   // (1,3)
    float* out = (float*)d_out;                  // 65536 f32, [w*256+h]
    float* params = (float*)d_ws;                // 4 floats scratch

    render_kernel<<<dim3(1024), dim3(256), 0, stream>>>(vol, camR, camT, out);
    reduce_kernel<<<dim3(1), dim3(1024), 0, stream>>>(out, params);
    finalize_kernel<<<dim3(256), dim3(256), 0, stream>>>(out, params);
}

// Round 2
// 59.136 us; speedup vs baseline: 1.2957x; 1.2957x over previous
//
#include <hip/hip_runtime.h>

// DirectVolumeStratifiedFrontToBackRenderer — MI355X
// Ray-march 256x256 rays x 320 samples through a 256^3 f32 volume.
// alpha is constant 0.1 inside the [-1,1]^3 local cube, so outside samples
// are exact no-ops (f32: 1-0.1f+1e-10 == 0.9f, 1+1e-10 == 1.0f).
// Output = per-image standardize + minmax, written at out[w*256+h].
//
// R1: SEGS 4->8 (8192 waves = full CU capacity), paired-x float2 gathers
// (8->4 loads/sample), conservative ray/box interval skip (+/-1 step margin,
// exact per-sample predicate retained).

#define SEGS 8
#define PPT 40   // 320 / SEGS

__global__ __launch_bounds__(512) void render_kernel(
    const float* __restrict__ vol,
    const float* __restrict__ camR,
    const float* __restrict__ camT,
    float* __restrict__ gray)
{
    const int lane = threadIdx.x & 63;
    const int seg  = threadIdx.x >> 6;
    const int pix  = blockIdx.x * 64 + lane;
    const int w = pix & 255;
    const int h = pix >> 8;

    // camera (B=1). Rt = R^T; origin = -Rt*T; dir = Rt*dir_cam.
    const float R00=camR[0],R01=camR[1],R02=camR[2];
    const float R10=camR[3],R11=camR[4],R12=camR[5];
    const float R20=camR[6],R21=camR[7],R22=camR[8];
    const float T0=camT[0],T1=camT[1],T2=camT[2];

    const float ox = -(R00*T0 + R10*T1 + R20*T2);
    const float oy = -(R01*T0 + R11*T1 + R21*T2);
    const float oz = -(R02*T0 + R12*T1 + R22*T2);

    const float FOVT = 0.57735026918962576f;   // tan(30 deg)
    const float gx = -1.0f + w * (2.0f/255.0f);
    const float gy = -1.0f + h * (2.0f/255.0f);
    const float dcx = gx*FOVT, dcy = gy*FOVT;  // dcz = 1

    const float dx = R00*dcx + R10*dcy + R20;
    const float dy = R01*dcx + R11*dcy + R21;
    const float dz = R02*dcx + R12*dcy + R22;

    // half = 255 * (3/256) * 0.5 = 1.494140625 (exact in f32)
    const float H = 1.494140625f;
    const float inv_half = (float)(1.0 / 1.494140625);
    const float DSTEP = 4.0f / 319.0f;
    const float INV_DSTEP = 319.0f / 4.0f;

    const int p0 = seg * PPT;

    // ---- conservative ray/box slab clip (world units), +/-1 step margin ----
    float tlo = 2.0f + (float)p0 * DSTEP;
    float thi = 2.0f + (float)(p0 + PPT - 1) * DSTEP;
    bool nonempty = true;
    {
        const float o3[3] = {ox, oy, oz};
        const float d3[3] = {dx, dy, dz};
        #pragma unroll
        for (int a = 0; a < 3; ++a) {
            const float o = o3[a], dc = d3[a];
            if (fabsf(dc) > 1e-8f) {
                const float r  = 1.0f / dc;
                const float ta = (-H - o) * r;
                const float tb = ( H - o) * r;
                tlo = fmaxf(tlo, fminf(ta, tb));
                thi = fminf(thi, fmaxf(ta, tb));
            } else if (fabsf(o) > H) {
                nonempty = false;
            }
        }
    }
    int ilo = 1, ihi = 0;
    if (nonempty && thi >= tlo) {
        ilo = max(p0,           (int)floorf((tlo - 2.0f) * INV_DSTEP) - 1);
        ihi = min(p0 + PPT - 1, (int)ceilf ((thi - 2.0f) * INV_DSTEP) + 1);
    }

    float T = 1.0f;
    float rgb = 0.0f;

    #pragma unroll 2
    for (int i = ilo; i <= ihi; ++i) {
        const float d = 2.0f + (float)i * DSTEP;
        const float px = fmaf(dx, d, ox) * inv_half;
        const float py = fmaf(dy, d, oy) * inv_half;
        const float pz = fmaf(dz, d, oz) * inv_half;
        if (fabsf(px) <= 1.0f && fabsf(py) <= 1.0f && fabsf(pz) <= 1.0f) {
            const float fx = (px + 1.0f) * 127.5f;
            const float fy = (py + 1.0f) * 127.5f;
            const float fz = (pz + 1.0f) * 127.5f;
            const float x0f = floorf(fx), y0f = floorf(fy), z0f = floorf(fz);
            const float wy = fy - y0f, wz = fz - z0f;
            int x0 = (int)x0f, y0 = (int)y0f, z0 = (int)z0f;
            y0 = max(0, min(y0, 255));
            z0 = max(0, min(z0, 255));
            // paired-x base: xb in [0,254]; wx = fx - xb gives exact result
            // (if x0==255 then wx==1 -> weight lands fully on v[255]).
            const int xb = max(0, min(x0, 254));
            const float wx = fx - (float)xb;
            const int y1 = min(y0 + 1, 255);
            const int z1 = min(z0 + 1, 255);
            const int zy00 = (z0*256 + y0) << 8;
            const int zy01 = (z0*256 + y1) << 8;
            const int zy10 = (z1*256 + y0) << 8;
            const int zy11 = (z1*256 + y1) << 8;
            const float2 p00 = *reinterpret_cast<const float2*>(vol + zy00 + xb);
            const float2 p01 = *reinterpret_cast<const float2*>(vol + zy01 + xb);
            const float2 p10 = *reinterpret_cast<const float2*>(vol + zy10 + xb);
            const float2 p11 = *reinterpret_cast<const float2*>(vol + zy11 + xb);
            const float c00 = fmaf(wx, p00.y - p00.x, p00.x);
            const float c01 = fmaf(wx, p01.y - p01.x, p01.x);
            const float c10 = fmaf(wx, p10.y - p10.x, p10.x);
            const float c11 = fmaf(wx, p11.y - p11.x, p11.x);
            const float c0 = fmaf(wy, c01 - c00, c00);
            const float c1 = fmaf(wy, c11 - c10, c10);
            const float v  = fmaf(wz, c1 - c0, c0);
            rgb = fmaf(0.1f * T, v, rgb);
            T *= 0.9f;
        }
        // outside: trans multiplier (1 + 1e-10) == 1.0f in f32 -> no-op
    }

    __shared__ float s_rgb[SEGS][64];
    __shared__ float s_T[SEGS][64];
    s_rgb[seg][lane] = rgb;
    s_T[seg][lane]   = T;
    __syncthreads();

    if (threadIdx.x < 64) {
        const int l = threadIdx.x;
        float total = s_rgb[0][l];
        float Ta    = s_T[0][l];
        #pragma unroll
        for (int s = 1; s < SEGS; ++s) {
            total = fmaf(Ta, s_rgb[s][l], total);
            Ta *= s_T[s][l];
        }
        const int pp = blockIdx.x * 64 + l;
        const int ww = pp & 255, hh = pp >> 8;
        // screen = transpose(rgba,(0,3,2,1)) -> out[w*256 + h]
        gray[ww * 256 + hh] = total;
    }
}

__global__ __launch_bounds__(1024) void reduce_kernel(
    const float* __restrict__ g, float* __restrict__ params)
{
    __shared__ double s_sum[1024];
    __shared__ double s_sq[1024];
    __shared__ float  s_mn[1024];
    __shared__ float  s_mx[1024];

    const int tid = threadIdx.x;
    double sum = 0.0, sq = 0.0;
    float mn = 3.4e38f, mx = -3.4e38f;
    for (int i = tid; i < 65536; i += 1024) {
        const float v = g[i];
        sum += (double)v;
        sq  += (double)v * (double)v;
        mn = fminf(mn, v);
        mx = fmaxf(mx, v);
    }
    s_sum[tid] = sum; s_sq[tid] = sq; s_mn[tid] = mn; s_mx[tid] = mx;
    __syncthreads();
    for (int s = 512; s > 0; s >>= 1) {
        if (tid < s) {
            s_sum[tid] += s_sum[tid + s];
            s_sq[tid]  += s_sq[tid + s];
            s_mn[tid]   = fminf(s_mn[tid], s_mn[tid + s]);
            s_mx[tid]   = fmaxf(s_mx[tid], s_mx[tid + s]);
        }
        __syncthreads();
    }
    if (tid == 0) {
        const double N = 65536.0;
        const double mean = s_sum[0] / N;
        double var = (s_sq[0] - s_sum[0] * s_sum[0] / N) / (N - 1.0);
        if (var < 0.0) var = 0.0;
        params[0] = (float)mean;
        params[1] = (float)sqrt(var) + 1e-8f;   // std(ddof=1) + EPS
        params[2] = s_mn[0];
        params[3] = s_mx[0];
    }
}

__global__ __launch_bounds__(256) void finalize_kernel(
    float* __restrict__ g, const float* __restrict__ params)
{
    const int i = blockIdx.x * 256 + threadIdx.x;
    const float mean = params[0], sd = params[1];
    const float mn = params[2],  mx = params[3];
    const float z    = (g[i] - mean) / sd;
    const float zmin = (mn   - mean) / sd;
    const float zmax = (mx   - mean) / sd;
    g[i] = (z - zmin + 1e-8f) / (zmax - zmin + 1e-8f);
}

extern "C" void kernel_launch(void* const* d_in, const int* in_sizes, int n_in,
                              void* d_out, int out_size, void* d_ws, size_t ws_size,
                              hipStream_t stream)
{
    const float* vol  = (const float*)d_in[0];   // (1,1,256,256,256) f32
    const float* camR = (const float*)d_in[1];   // (1,3,3)
    const float* camT = (const float*)d_in[2];   // (1,3)
    float* out = (float*)d_out;                  // 65536 f32, [w*256+h]
    float* params = (float*)d_ws;                // 4 floats scratch

    render_kernel<<<dim3(1024), dim3(512), 0, stream>>>(vol, camR, camT, out);
    reduce_kernel<<<dim3(1), dim3(1024), 0, stream>>>(out, params);
    finalize_kernel<<<dim3(256), dim3(256), 0, stream>>>(out, params);
}

// Round 3
// 35.241 us; speedup vs baseline: 2.1743x; 1.6781x over previous
//
#include <hip/hip_runtime.h>

// DirectVolumeStratifiedFrontToBackRenderer — MI355X
// Ray-march 256x256 rays x 320 samples through a 256^3 f32 volume.
// alpha = const 0.1 inside the [-1,1]^3 local cube (f32: 1-0.1f+1e-10==0.9f,
// 1+1e-10==1.0f) so outside samples are exact no-ops and transmittance before
// sample i is 0.9^(i-i0), where [i0,i1] is the (exact, monotone-interval)
// inside range. Output = standardize + minmax at out[w*256+h].
//
// R2: stratified 8-threads-per-ray over the exact interval (perfect load
// balance, no per-sample predicate, no serial T chain); per-block stats
// partials fused into render; single-CU reduce kernel deleted (finalize
// blocks redundantly reduce 1024 partials).

#define G    8    // threads per ray
#define BLK  512  // G waves of 64 pixels

struct Partial { double sum; double sq; float mn; float mx; };

__global__ __launch_bounds__(BLK) void render_kernel(
    const float* __restrict__ vol,
    const float* __restrict__ camR,
    const float* __restrict__ camT,
    float* __restrict__ gray,
    Partial* __restrict__ parts)
{
    const int lane = threadIdx.x & 63;
    const int g    = threadIdx.x >> 6;
    const int pix  = blockIdx.x * 64 + lane;
    const int w = pix & 255;
    const int h = pix >> 8;

    // camera (B=1). Rt = R^T; origin = -Rt*T; dir = Rt*dir_cam.
    const float R00=camR[0],R01=camR[1],R02=camR[2];
    const float R10=camR[3],R11=camR[4],R12=camR[5];
    const float R20=camR[6],R21=camR[7],R22=camR[8];
    const float T0=camT[0],T1=camT[1],T2=camT[2];

    const float ox = -(R00*T0 + R10*T1 + R20*T2);
    const float oy = -(R01*T0 + R11*T1 + R21*T2);
    const float oz = -(R02*T0 + R12*T1 + R22*T2);

    const float FOVT = 0.57735026918962576f;   // tan(30 deg)
    const float gx = -1.0f + w * (2.0f/255.0f);
    const float gy = -1.0f + h * (2.0f/255.0f);
    const float dcx = gx*FOVT, dcy = gy*FOVT;  // dcz = 1

    const float dx = R00*dcx + R10*dcy + R20;
    const float dy = R01*dcx + R11*dcy + R21;
    const float dz = R02*dcx + R12*dcy + R22;

    // half = 255 * (3/256) * 0.5 = 1.494140625 (exact in f32)
    const float H = 1.494140625f;
    const float inv_half = (float)(1.0 / 1.494140625);
    const float DSTEP = 4.0f / 319.0f;
    const float INV_DSTEP = 319.0f / 4.0f;

    // ---- conservative ray/box slab clip over the full range, +/-2 margin ----
    float tlo = 2.0f;
    float thi = 6.0f;
    bool nonempty = true;
    {
        const float o3[3] = {ox, oy, oz};
        const float d3[3] = {dx, dy, dz};
        #pragma unroll
        for (int a = 0; a < 3; ++a) {
            const float o = o3[a], dc = d3[a];
            if (fabsf(dc) > 1e-8f) {
                const float r  = 1.0f / dc;
                const float ta = (-H - o) * r;
                const float tb = ( H - o) * r;
                tlo = fmaxf(tlo, fminf(ta, tb));
                thi = fminf(thi, fmaxf(ta, tb));
            } else if (fabsf(o) > H) {
                nonempty = false;
            }
        }
    }

    // exact inside predicate — bit-identical to the validated R1 kernel
    auto inside_i = [&](int i) -> bool {
        const float d = 2.0f + (float)i * DSTEP;
        const float px = fmaf(dx, d, ox) * inv_half;
        const float py = fmaf(dy, d, oy) * inv_half;
        const float pz = fmaf(dz, d, oz) * inv_half;
        return fabsf(px) <= 1.0f && fabsf(py) <= 1.0f && fabsf(pz) <= 1.0f;
    };

    int i0 = 0, i1 = -1;
    if (nonempty && thi >= tlo) {
        int ilo = max(0,   (int)floorf((tlo - 2.0f) * INV_DSTEP) - 2);
        int ihi = min(319, (int)ceilf ((thi - 2.0f) * INV_DSTEP) + 2);
        i0 = ilo; while (i0 <= ihi && !inside_i(i0)) ++i0;
        i1 = ihi; while (i1 >= i0 && !inside_i(i1)) --i1;
        if (i0 > ihi) { i0 = 0; i1 = -1; }
    }

    // thread g handles i = i0+g, i0+g+G, ... with weight 0.9^(i-i0)
    float s = 0.0f;
    const int rem = i1 - i0 - g;                 // >=0 iff this thread has work
    const int kn  = (rem >= 0) ? (rem / G + 1) : 0;

    float wgt = 1.0f;
    #pragma unroll
    for (int j = 0; j < G - 1; ++j) if (j < g) wgt *= 0.9f;
    const float WSTEP = 0.43046721f;             // 0.9^8

    int i = i0 + g;
    #pragma unroll 2
    for (int k = 0; k < kn; ++k, i += G) {
        const float d = 2.0f + (float)i * DSTEP;
        const float px = fmaf(dx, d, ox) * inv_half;
        const float py = fmaf(dy, d, oy) * inv_half;
        const float pz = fmaf(dz, d, oz) * inv_half;
        const float fx = (px + 1.0f) * 127.5f;
        const float fy = (py + 1.0f) * 127.5f;
        const float fz = (pz + 1.0f) * 127.5f;
        const float x0f = floorf(fx), y0f = floorf(fy), z0f = floorf(fz);
        const float wy = fy - y0f, wz = fz - z0f;
        int y0 = (int)y0f, z0 = (int)z0f;
        y0 = max(0, min(y0, 255));
        z0 = max(0, min(z0, 255));
        // paired-x base: xb in [0,254]; wx = fx - xb exact at the x=255 edge.
        const int xb = max(0, min((int)x0f, 254));
        const float wx = fx - (float)xb;
        const int y1 = min(y0 + 1, 255);
        const int z1 = min(z0 + 1, 255);
        const int zy00 = (z0*256 + y0) << 8;
        const int zy01 = (z0*256 + y1) << 8;
        const int zy10 = (z1*256 + y0) << 8;
        const int zy11 = (z1*256 + y1) << 8;
        const float2 p00 = *reinterpret_cast<const float2*>(vol + zy00 + xb);
        const float2 p01 = *reinterpret_cast<const float2*>(vol + zy01 + xb);
        const float2 p10 = *reinterpret_cast<const float2*>(vol + zy10 + xb);
        const float2 p11 = *reinterpret_cast<const float2*>(vol + zy11 + xb);
        const float c00 = fmaf(wx, p00.y - p00.x, p00.x);
        const float c01 = fmaf(wx, p01.y - p01.x, p01.x);
        const float c10 = fmaf(wx, p10.y - p10.x, p10.x);
        const float c11 = fmaf(wx, p11.y - p11.x, p11.x);
        const float c0 = fmaf(wy, c01 - c00, c00);
        const float c1 = fmaf(wy, c11 - c10, c10);
        const float v  = fmaf(wz, c1 - c0, c0);
        s = fmaf(wgt, v, s);
        wgt *= WSTEP;
    }

    __shared__ float s_part[G][64];
    s_part[g][lane] = s;
    __syncthreads();

    if (threadIdx.x < 64) {
        const int l = threadIdx.x;
        float total = 0.0f;
        #pragma unroll
        for (int q = 0; q < G; ++q) total += s_part[q][l];
        total *= 0.1f;

        const int pp = blockIdx.x * 64 + l;
        const int ww = pp & 255, hh = pp >> 8;
        // screen = transpose(rgba,(0,3,2,1)) -> out[w*256 + h]
        gray[ww * 256 + hh] = total;

        // per-block stats partial (wave-wide shuffle reduce over 64 totals)
        double sum = (double)total;
        double sq  = (double)total * (double)total;
        float  mn = total, mx = total;
        #pragma unroll
        for (int off = 32; off > 0; off >>= 1) {
            sum += __shfl_xor(sum, off);
            sq  += __shfl_xor(sq,  off);
            mn = fminf(mn, __shfl_xor(mn, off));
            mx = fmaxf(mx, __shfl_xor(mx, off));
        }
        if (l == 0) {
            parts[blockIdx.x].sum = sum;
            parts[blockIdx.x].sq  = sq;
            parts[blockIdx.x].mn  = mn;
            parts[blockIdx.x].mx  = mx;
        }
    }
}

__global__ __launch_bounds__(1024) void finalize_kernel(
    float* __restrict__ gray, const Partial* __restrict__ parts)
{
    const int tid = threadIdx.x;

    // each block redundantly reduces the 1024 render-block partials
    Partial p = parts[tid];
    double sum = p.sum, sq = p.sq;
    float  mn = p.mn,  mx = p.mx;
    #pragma unroll
    for (int off = 32; off > 0; off >>= 1) {
        sum += __shfl_xor(sum, off);
        sq  += __shfl_xor(sq,  off);
        mn = fminf(mn, __shfl_xor(mn, off));
        mx = fmaxf(mx, __shfl_xor(mx, off));
    }
    __shared__ double s_sum[16], s_sq[16];
    __shared__ float  s_mn[16],  s_mx[16];
    const int wid = tid >> 6;
    if ((tid & 63) == 0) { s_sum[wid]=sum; s_sq[wid]=sq; s_mn[wid]=mn; s_mx[wid]=mx; }
    __syncthreads();

    __shared__ float fpar[4];
    if (tid == 0) {
        double S = 0.0, Q = 0.0;
        float MN = 3.4e38f, MX = -3.4e38f;
        #pragma unroll
        for (int q = 0; q < 16; ++q) {
            S += s_sum[q]; Q += s_sq[q];
            MN = fminf(MN, s_mn[q]); MX = fmaxf(MX, s_mx[q]);
        }
        const double N = 65536.0;
        const double mean = S / N;
        double var = (Q - S * S / N) / (N - 1.0);
        if (var < 0.0) var = 0.0;
        fpar[0] = (float)mean;
        fpar[1] = (float)sqrt(var) + 1e-8f;    // std(ddof=1) + EPS
        fpar[2] = MN;
        fpar[3] = MX;
    }
    __syncthreads();

    const float mean = fpar[0], sd = fpar[1];
    const float mnv = fpar[2],  mxv = fpar[3];
    const int idx = blockIdx.x * 1024 + tid;
    const float z    = (gray[idx] - mean) / sd;
    const float zmin = (mnv - mean) / sd;
    const float zmax = (mxv - mean) / sd;
    gray[idx] = (z - zmin + 1e-8f) / (zmax - zmin + 1e-8f);
}

extern "C" void kernel_launch(void* const* d_in, const int* in_sizes, int n_in,
                              void* d_out, int out_size, void* d_ws, size_t ws_size,
                              hipStream_t stream)
{
    const float* vol  = (const float*)d_in[0];   // (1,1,256,256,256) f32
    const float* camR = (const float*)d_in[1];   // (1,3,3)
    const float* camT = (const float*)d_in[2];   // (1,3)
    float* out = (float*)d_out;                  // 65536 f32, [w*256+h]
    Partial* parts = (Partial*)d_ws;             // 1024 * 24 B scratch

    render_kernel<<<dim3(1024), dim3(BLK), 0, stream>>>(vol, camR, camT, out, parts);
    finalize_kernel<<<dim3(64), dim3(1024), 0, stream>>>(out, parts);
}

// Round 4
// 34.728 us; speedup vs baseline: 2.2064x; 1.0148x over previous
//
#include <hip/hip_runtime.h>

// DirectVolumeStratifiedFrontToBackRenderer — MI355X
// Ray-march 256x256 rays x 320 samples through a 256^3 f32 volume.
// alpha = const 0.1 inside the [-1,1]^3 local cube (f32: 1-0.1f+1e-10==0.9f,
// 1+1e-10==1.0f) so outside samples are exact no-ops and transmittance before
// sample i is 0.9^(i-i0) on the exact inside interval [i0,i1] (monotone in i).
// Output = standardize + minmax at out[w*256+h].
//
// R3: G=16 depth-threads/ray in 1024-thread blocks -> 1024 blocks vs 512
// resident slots (2x oversubscription, HW backfill fixes the ~45% occupancy
// hole from row-dependent work). Incremental affine fx/fy/fz in the hot loop
// (3 adds replace ~15 ops). Volume is L3-resident across replays; more waves
// = more latency hiding on L2/L3 gathers.

#define G    16   // threads per ray
#define BLK  1024 // G waves of 64 pixels

struct Partial { double sum; double sq; float mn; float mx; };

__global__ __launch_bounds__(BLK) void render_kernel(
    const float* __restrict__ vol,
    const float* __restrict__ camR,
    const float* __restrict__ camT,
    float* __restrict__ gray,
    Partial* __restrict__ parts)
{
    const int lane = threadIdx.x & 63;
    const int g    = threadIdx.x >> 6;
    const int pix  = blockIdx.x * 64 + lane;
    const int w = pix & 255;
    const int h = pix >> 8;

    // camera (B=1). Rt = R^T; origin = -Rt*T; dir = Rt*dir_cam.
    const float R00=camR[0],R01=camR[1],R02=camR[2];
    const float R10=camR[3],R11=camR[4],R12=camR[5];
    const float R20=camR[6],R21=camR[7],R22=camR[8];
    const float T0=camT[0],T1=camT[1],T2=camT[2];

    const float ox = -(R00*T0 + R10*T1 + R20*T2);
    const float oy = -(R01*T0 + R11*T1 + R21*T2);
    const float oz = -(R02*T0 + R12*T1 + R22*T2);

    const float FOVT = 0.57735026918962576f;   // tan(30 deg)
    const float gx = -1.0f + w * (2.0f/255.0f);
    const float gy = -1.0f + h * (2.0f/255.0f);
    const float dcx = gx*FOVT, dcy = gy*FOVT;  // dcz = 1

    const float dx = R00*dcx + R10*dcy + R20;
    const float dy = R01*dcx + R11*dcy + R21;
    const float dz = R02*dcx + R12*dcy + R22;

    // half = 255 * (3/256) * 0.5 = 1.494140625 (exact in f32)
    const float H = 1.494140625f;
    const float inv_half = (float)(1.0 / 1.494140625);
    const float DSTEP = 4.0f / 319.0f;
    const float INV_DSTEP = 319.0f / 4.0f;

    // ---- conservative ray/box slab clip over the full range, +/-2 margin ----
    float tlo = 2.0f;
    float thi = 6.0f;
    bool nonempty = true;
    {
        const float o3[3] = {ox, oy, oz};
        const float d3[3] = {dx, dy, dz};
        #pragma unroll
        for (int a = 0; a < 3; ++a) {
            const float o = o3[a], dc = d3[a];
            if (fabsf(dc) > 1e-8f) {
                const float r  = 1.0f / dc;
                const float ta = (-H - o) * r;
                const float tb = ( H - o) * r;
                tlo = fmaxf(tlo, fminf(ta, tb));
                thi = fminf(thi, fmaxf(ta, tb));
            } else if (fabsf(o) > H) {
                nonempty = false;
            }
        }
    }

    // exact inside predicate — same forms as the validated R1/R2 kernels
    auto inside_i = [&](int i) -> bool {
        const float d = 2.0f + (float)i * DSTEP;
        const float px = fmaf(dx, d, ox) * inv_half;
        const float py = fmaf(dy, d, oy) * inv_half;
        const float pz = fmaf(dz, d, oz) * inv_half;
        return fabsf(px) <= 1.0f && fabsf(py) <= 1.0f && fabsf(pz) <= 1.0f;
    };

    int i0 = 0, i1 = -1;
    if (nonempty && thi >= tlo) {
        int ilo = max(0,   (int)floorf((tlo - 2.0f) * INV_DSTEP) - 2);
        int ihi = min(319, (int)ceilf ((thi - 2.0f) * INV_DSTEP) + 2);
        i0 = ilo; while (i0 <= ihi && !inside_i(i0)) ++i0;
        i1 = ihi; while (i1 >= i0 && !inside_i(i1)) --i1;
        if (i0 > ihi) { i0 = 0; i1 = -1; }
    }

    // thread g handles i = i0+g, i0+g+G, ... with weight 0.9^(i-i0)
    float s = 0.0f;
    const int rem = i1 - i0 - g;                 // >=0 iff this thread has work
    const int kn  = (rem >= 0) ? (rem / G + 1) : 0;

    float wgt = 1.0f;
    #pragma unroll
    for (int j = 0; j < G - 1; ++j) if (j < g) wgt *= 0.9f;
    const float WSTEP = 0.1853020188851841f;     // 0.9^16 (exact decimal)

    // incremental affine voxel coords: f = X*SC + 127.5, X = fmaf(d_,t,o_)
    const float SC = inv_half * 127.5f;
    const float d0 = 2.0f + (float)(i0 + g) * DSTEP;
    const float tstep = DSTEP * (float)G;
    float fx = fmaf(fmaf(dx, d0, ox), SC, 127.5f);
    float fy = fmaf(fmaf(dy, d0, oy), SC, 127.5f);
    float fz = fmaf(fmaf(dz, d0, oz), SC, 127.5f);
    const float sx = dx * tstep * SC;
    const float sy = dy * tstep * SC;
    const float sz = dz * tstep * SC;

    #pragma unroll 2
    for (int k = 0; k < kn; ++k) {
        const float x0f = floorf(fx), y0f = floorf(fy), z0f = floorf(fz);
        const float wy = fy - y0f, wz = fz - z0f;
        // paired-x base in [0,254]; wx = fx - xb is exact at both x edges.
        const int xb  = min(max((int)x0f, 0), 254);
        const float wx = fx - (float)xb;
        const int y0 = max((int)y0f, 0);
        const int z0 = max((int)z0f, 0);
        const int y1 = min(y0 + 1, 255);
        const int z1 = min(z0 + 1, 255);
        const int y0s = y0 << 8, y1s = y1 << 8;
        const int bz0 = (z0 << 16) + xb;
        const int bz1 = (z1 << 16) + xb;
        const float2 p00 = *reinterpret_cast<const float2*>(vol + (bz0 + y0s));
        const float2 p01 = *reinterpret_cast<const float2*>(vol + (bz0 + y1s));
        const float2 p10 = *reinterpret_cast<const float2*>(vol + (bz1 + y0s));
        const float2 p11 = *reinterpret_cast<const float2*>(vol + (bz1 + y1s));
        fx += sx; fy += sy; fz += sz;
        const float c00 = fmaf(wx, p00.y - p00.x, p00.x);
        const float c01 = fmaf(wx, p01.y - p01.x, p01.x);
        const float c10 = fmaf(wx, p10.y - p10.x, p10.x);
        const float c11 = fmaf(wx, p11.y - p11.x, p11.x);
        const float c0 = fmaf(wy, c01 - c00, c00);
        const float c1 = fmaf(wy, c11 - c10, c10);
        const float v  = fmaf(wz, c1 - c0, c0);
        s = fmaf(wgt, v, s);
        wgt *= WSTEP;
    }

    __shared__ float s_part[G][64];
    s_part[g][lane] = s;
    __syncthreads();

    if (threadIdx.x < 64) {
        const int l = threadIdx.x;
        float total = 0.0f;
        #pragma unroll
        for (int q = 0; q < G; ++q) total += s_part[q][l];
        total *= 0.1f;

        const int pp = blockIdx.x * 64 + l;
        const int ww = pp & 255, hh = pp >> 8;
        // screen = transpose(rgba,(0,3,2,1)) -> out[w*256 + h]
        gray[ww * 256 + hh] = total;

        // per-block stats partial (wave-wide shuffle reduce over 64 totals)
        double sum = (double)total;
        double sq  = (double)total * (double)total;
        float  mn = total, mx = total;
        #pragma unroll
        for (int off = 32; off > 0; off >>= 1) {
            sum += __shfl_xor(sum, off);
            sq  += __shfl_xor(sq,  off);
            mn = fminf(mn, __shfl_xor(mn, off));
            mx = fmaxf(mx, __shfl_xor(mx, off));
        }
        if (l == 0) {
            parts[blockIdx.x].sum = sum;
            parts[blockIdx.x].sq  = sq;
            parts[blockIdx.x].mn  = mn;
            parts[blockIdx.x].mx  = mx;
        }
    }
}

__global__ __launch_bounds__(1024) void finalize_kernel(
    float* __restrict__ gray, const Partial* __restrict__ parts)
{
    const int tid = threadIdx.x;

    // each block redundantly reduces the 1024 render-block partials
    Partial p = parts[tid];
    double sum = p.sum, sq = p.sq;
    float  mn = p.mn,  mx = p.mx;
    #pragma unroll
    for (int off = 32; off > 0; off >>= 1) {
        sum += __shfl_xor(sum, off);
        sq  += __shfl_xor(sq,  off);
        mn = fminf(mn, __shfl_xor(mn, off));
        mx = fmaxf(mx, __shfl_xor(mx, off));
    }
    __shared__ double s_sum[16], s_sq[16];
    __shared__ float  s_mn[16],  s_mx[16];
    const int wid = tid >> 6;
    if ((tid & 63) == 0) { s_sum[wid]=sum; s_sq[wid]=sq; s_mn[wid]=mn; s_mx[wid]=mx; }
    __syncthreads();

    __shared__ float fpar[4];
    if (tid == 0) {
        double S = 0.0, Q = 0.0;
        float MN = 3.4e38f, MX = -3.4e38f;
        #pragma unroll
        for (int q = 0; q < 16; ++q) {
            S += s_sum[q]; Q += s_sq[q];
            MN = fminf(MN, s_mn[q]); MX = fmaxf(MX, s_mx[q]);
        }
        const double N = 65536.0;
        const double mean = S / N;
        double var = (Q - S * S / N) / (N - 1.0);
        if (var < 0.0) var = 0.0;
        fpar[0] = (float)mean;
        fpar[1] = (float)sqrt(var) + 1e-8f;    // std(ddof=1) + EPS
        fpar[2] = MN;
        fpar[3] = MX;
    }
    __syncthreads();

    const float mean = fpar[0], sd = fpar[1];
    const float mnv = fpar[2],  mxv = fpar[3];
    const int idx = blockIdx.x * 1024 + tid;
    const float z    = (gray[idx] - mean) / sd;
    const float zmin = (mnv - mean) / sd;
    const float zmax = (mxv - mean) / sd;
    gray[idx] = (z - zmin + 1e-8f) / (zmax - zmin + 1e-8f);
}

extern "C" void kernel_launch(void* const* d_in, const int* in_sizes, int n_in,
                              void* d_out, int out_size, void* d_ws, size_t ws_size,
                              hipStream_t stream)
{
    const float* vol  = (const float*)d_in[0];   // (1,1,256,256,256) f32
    const float* camR = (const float*)d_in[1];   // (1,3,3)
    const float* camT = (const float*)d_in[2];   // (1,3)
    float* out = (float*)d_out;                  // 65536 f32, [w*256+h]
    Partial* parts = (Partial*)d_ws;             // 1024 * 24 B scratch

    render_kernel<<<dim3(1024), dim3(BLK), 0, stream>>>(vol, camR, camT, out, parts);
    finalize_kernel<<<dim3(64), dim3(1024), 0, stream>>>(out, parts);
}